// Round 2
// baseline (1008.369 us; speedup 1.0000x reference)
//
#include <hip/hip_runtime.h>
#include <math.h>

#define LSEQ 512
#define CS 384
#define CZ 256
#define HD 16
#define NH 12
#define NQ 4
#define NV 8
#define NALL 1152   // 192*3 + 144*2 + 288
#define SHID 3648   // NH * 304
// column offsets inside P rows
#define OFF_Q 0
#define OFF_K 192
#define OFF_V 384
#define OFF_QP 576
#define OFF_KP 720
#define OFF_VP 864

#define WC_CONST 0.2357022603955158f  // sqrt(2/(9*4))
#define WL_CONST 0.5773502691896258f  // sqrt(1/3)

typedef __attribute__((ext_vector_type(8))) short bf16x8;
typedef __attribute__((ext_vector_type(4))) float f32x4;

__device__ __forceinline__ short f2bf(float f) {
  unsigned u = __builtin_bit_cast(unsigned, f);
  unsigned r = (u + 0x7FFF + ((u >> 16) & 1)) >> 16;
  return (short)r;
}

// ---------------- prep: R, t, c_h, padded bf16 Wb ----------------
__global__ void k_prep(const float* quat, const float* trsl, const float* scale,
                       const float* Wb, float* R, float* T, float* CH,
                       unsigned short* WBP) {
  int t = threadIdx.x;
  if (t < LSEQ) {
    float w = quat[t*4+0], x = quat[t*4+1], y = quat[t*4+2], z = quat[t*4+3];
    float inv = 1.0f / sqrtf(w*w + x*x + y*y + z*z);
    w *= inv; x *= inv; y *= inv; z *= inv;
    float* r = R + t*9;
    r[0] = 1.f - 2.f*(y*y + z*z); r[1] = 2.f*(x*y - w*z);       r[2] = 2.f*(x*z + w*y);
    r[3] = 2.f*(x*y + w*z);       r[4] = 1.f - 2.f*(x*x + z*z); r[5] = 2.f*(y*z - w*x);
    r[6] = 2.f*(x*z - w*y);       r[7] = 2.f*(y*z + w*x);       r[8] = 1.f - 2.f*(x*x + y*y);
    T[t*3+0] = trsl[t*3+0]; T[t*3+1] = trsl[t*3+1]; T[t*3+2] = trsl[t*3+2];
  }
  if (t < NH) {
    float sc = scale[t];
    float sp = (sc > 20.f) ? sc : logf(1.f + expf(sc));
    CH[t] = 0.5f * WC_CONST * sp;
  }
  if (t < CZ) {
    #pragma unroll
    for (int h = 0; h < 16; h++)
      WBP[t*16 + h] = (h < NH) ? (unsigned short)f2bf(Wb[t*NH + h]) : (unsigned short)0;
  }
}

// ---------------- concat weights ----------------
__global__ void k_concat(const float* Wq, const float* Wk, const float* Wv,
                         const float* Wqp, const float* Wkp, const float* Wvp,
                         float* Wcat) {
  int idx = blockIdx.x * 256 + threadIdx.x;
  if (idx >= CS * NALL) return;
  int r = idx / NALL, c = idx % NALL;
  float v;
  if (c < 192)       v = Wq [r*192 + c];
  else if (c < 384)  v = Wk [r*192 + (c-192)];
  else if (c < 576)  v = Wv [r*192 + (c-384)];
  else if (c < 720)  v = Wqp[r*144 + (c-576)];
  else if (c < 864)  v = Wkp[r*144 + (c-720)];
  else               v = Wvp[r*288 + (c-864)];
  Wcat[idx] = v;
}

// ---------------- generic f32 GEMM: C = A@B (+bias)(relu), split-K via atomics ----------------
__global__ __launch_bounds__(256) void k_gemm(
    const float* A, const float* B, float* C, const float* bias,
    int M, int N, int K, int lda, int ldb, int ldc,
    long strideA, long strideB, long strideC,
    int splitk, int relu) {
  int zb = blockIdx.z;
  int batch = zb / splitk, ks = zb % splitk;
  A += (long)batch * strideA;
  B += (long)batch * strideB;
  C += (long)batch * strideC;
  int Ksub = K / splitk;
  int kbeg = ks * Ksub;

  __shared__ __align__(16) float As[16][68];
  __shared__ __align__(16) float Bs[16][68];
  int t = threadIdx.x;
  int m0 = blockIdx.y * 64, n0 = blockIdx.x * 64;
  int arow = t >> 2,  akq = (t & 3) * 4;
  int bkk  = t >> 4,  bnq = (t & 15) * 4;
  int ty = (t >> 4) * 4, tx = (t & 15) * 4;
  float acc[4][4];
  #pragma unroll
  for (int r = 0; r < 4; r++)
    #pragma unroll
    for (int c = 0; c < 4; c++) acc[r][c] = 0.f;

  for (int kb = kbeg; kb < kbeg + Ksub; kb += 16) {
    float4 av = *(const float4*)&A[(long)(m0 + arow) * lda + kb + akq];
    float4 bv;
    const float* brow = B + (long)(kb + bkk) * ldb;
    if (n0 + bnq + 3 < N) {
      bv = *(const float4*)&brow[n0 + bnq];
    } else {
      float tmp[4];
      #pragma unroll
      for (int u = 0; u < 4; u++) tmp[u] = (n0 + bnq + u < N) ? brow[n0 + bnq + u] : 0.f;
      bv = make_float4(tmp[0], tmp[1], tmp[2], tmp[3]);
    }
    __syncthreads();
    As[akq+0][arow] = av.x; As[akq+1][arow] = av.y;
    As[akq+2][arow] = av.z; As[akq+3][arow] = av.w;
    *(float4*)&Bs[bkk][bnq] = bv;
    __syncthreads();
    #pragma unroll
    for (int kk = 0; kk < 16; kk++) {
      float4 a4 = *(float4*)&As[kk][ty];
      float4 b4 = *(float4*)&Bs[kk][tx];
      acc[0][0] += a4.x*b4.x; acc[0][1] += a4.x*b4.y; acc[0][2] += a4.x*b4.z; acc[0][3] += a4.x*b4.w;
      acc[1][0] += a4.y*b4.x; acc[1][1] += a4.y*b4.y; acc[1][2] += a4.y*b4.z; acc[1][3] += a4.y*b4.w;
      acc[2][0] += a4.z*b4.x; acc[2][1] += a4.z*b4.y; acc[2][2] += a4.z*b4.z; acc[2][3] += a4.z*b4.w;
      acc[3][0] += a4.w*b4.x; acc[3][1] += a4.w*b4.y; acc[3][2] += a4.w*b4.z; acc[3][3] += a4.w*b4.w;
    }
  }

  if (splitk == 1) {
    #pragma unroll
    for (int r = 0; r < 4; r++) {
      int m = m0 + ty + r;
      #pragma unroll
      for (int c = 0; c < 4; c++) {
        int n = n0 + tx + c;
        if (n < N) {
          float v = acc[r][c] + (bias ? bias[n] : 0.f);
          if (relu) v = fmaxf(v, 0.f);
          C[(long)m * ldc + n] = v;
        }
      }
    }
  } else {
    #pragma unroll
    for (int r = 0; r < 4; r++) {
      int m = m0 + ty + r;
      #pragma unroll
      for (int c = 0; c < 4; c++) {
        int n = n0 + tx + c;
        if (n < N) {
          float v = acc[r][c] + ((ks == 0 && bias) ? bias[n] : 0.f);
          atomicAdd(&C[(long)m * ldc + n], v);
        }
      }
    }
  }
}

// ---------------- rigid transforms: QPP, KPP, VB=[v|vpp] ----------------
__global__ void k_trans(const float* P, const float* R, const float* T,
                        float* QPP, float* KPP, float* VB) {
  int idx = blockIdx.x * 256 + threadIdx.x;
  if (idx >= LSEQ * NH) return;
  int l = idx / NH, h = idx % NH;
  const float* r = R + l*9;
  float t0 = T[l*3], t1 = T[l*3+1], t2 = T[l*3+2];
  const float* prow = P + (long)l * NALL;
  #pragma unroll
  for (int pq = 0; pq < NQ; pq++) {
    const float* x = prow + OFF_QP + h*12 + pq*3;
    float a = x[0], b = x[1], c = x[2];
    float* o = QPP + l*144 + h*12 + pq*3;
    o[0] = r[0]*a + r[1]*b + r[2]*c + t0;
    o[1] = r[3]*a + r[4]*b + r[5]*c + t1;
    o[2] = r[6]*a + r[7]*b + r[8]*c + t2;
  }
  #pragma unroll
  for (int pq = 0; pq < NQ; pq++) {
    const float* x = prow + OFF_KP + h*12 + pq*3;
    float a = x[0], b = x[1], c = x[2];
    float* o = KPP + l*144 + h*12 + pq*3;
    o[0] = r[0]*a + r[1]*b + r[2]*c + t0;
    o[1] = r[3]*a + r[4]*b + r[5]*c + t1;
    o[2] = r[6]*a + r[7]*b + r[8]*c + t2;
  }
  float* vb = VB + ((long)(h * LSEQ + l)) * 40;
  #pragma unroll
  for (int d = 0; d < 16; d++) vb[d] = prow[OFF_V + h*16 + d];
  #pragma unroll
  for (int pv = 0; pv < NV; pv++) {
    const float* x = prow + OFF_VP + h*24 + pv*3;
    float a = x[0], b = x[1], c = x[2];
    vb[16 + 3*pv + 0] = r[0]*a + r[1]*b + r[2]*c + t0;
    vb[16 + 3*pv + 1] = r[3]*a + r[4]*b + r[5]*c + t1;
    vb[16 + 3*pv + 2] = r[6]*a + r[7]*b + r[8]*c + t2;
  }
}

// ---------------- b = z @ Wb via MFMA bf16, no LDS ----------------
// grid (512, 4), block 256. Each wave: 2 tiles of 16 j-rows.
// A-frag: lane supplies z[j0 + (l&15)][kt*32 + (l>>4)*8 + jj]
// B-frag: lane supplies Wb[kt*32 + (l>>4)*8 + jj][h = l&15] (padded to 16 cols)
// D: col(h) = l&15, row(j) = (l>>4)*4 + reg
__global__ __launch_bounds__(256) void k_bias_mfma(const float* zin,
    const unsigned short* WBP, float* Bb) {
  int i = blockIdx.x;
  int part = blockIdx.y;
  int t = threadIdx.x;
  int w = t >> 6, l = t & 63;
  int r = l & 15, kg = l >> 4;

  bf16x8 bfrag[8];
  #pragma unroll
  for (int kt = 0; kt < 8; kt++) {
    #pragma unroll
    for (int jj = 0; jj < 8; jj++) {
      int c = kt*32 + kg*8 + jj;
      bfrag[kt][jj] = (short)WBP[c*16 + r];
    }
  }

  #pragma unroll
  for (int tt = 0; tt < 2; tt++) {
    int j0 = part*128 + (w*2 + tt)*16;
    const float* zrow = zin + ((long)i*LSEQ + j0 + r) * CZ + kg*8;
    f32x4 acc = {0.f, 0.f, 0.f, 0.f};
    #pragma unroll
    for (int kt = 0; kt < 8; kt++) {
      float4 z0 = *(const float4*)(zrow + kt*32);
      float4 z1 = *(const float4*)(zrow + kt*32 + 4);
      bf16x8 af;
      af[0] = f2bf(z0.x); af[1] = f2bf(z0.y); af[2] = f2bf(z0.z); af[3] = f2bf(z0.w);
      af[4] = f2bf(z1.x); af[5] = f2bf(z1.y); af[6] = f2bf(z1.z); af[7] = f2bf(z1.w);
      acc = __builtin_amdgcn_mfma_f32_16x16x32_bf16(af, bfrag[kt], acc, 0, 0, 0);
    }
    if (r < NH) {
      int jbase = j0 + kg*4;
      float4 o = make_float4(acc[0], acc[1], acc[2], acc[3]);
      *(float4*)&Bb[((long)i*NH + r)*LSEQ + jbase] = o;
    }
  }
}

// ---------------- attention logits + softmax (4 barriers total) ----------------
// grid 512 (i), block 512 (j)
__global__ __launch_bounds__(512) void k_attn2(const float* P, const float* QPP,
    const float* KPP, const float* Bb, const float* CH, float* Aa) {
  int i = blockIdx.x, t = threadIdx.x;
  __shared__ __align__(16) float sq[192];
  __shared__ __align__(16) float sp[144];
  __shared__ float sch[NH];
  __shared__ float redm[8*NH], reds[8*NH];
  __shared__ float bcm[NH], bcs[NH];
  if (t < 192) sq[t] = P[(long)i * NALL + t];
  if (t < 144) sp[t] = QPP[i * 144 + t];
  if (t < NH)  sch[t] = CH[t];
  __syncthreads();
  int j = t, w = t >> 6;
  const float* krow_base = P + (long)j * NALL + OFF_K;
  const float* kpp_base  = KPP + j * 144;
  const float* bb_base   = Bb + (long)i * NH * LSEQ + j;
  float lg[NH];
  #pragma unroll
  for (int h = 0; h < NH; h++) {
    const float* krow = krow_base + h * HD;
    float4 q0 = *(float4*)&sq[h*16+0],  q1 = *(float4*)&sq[h*16+4];
    float4 q2 = *(float4*)&sq[h*16+8],  q3 = *(float4*)&sq[h*16+12];
    float4 k0 = *(const float4*)&krow[0],  k1 = *(const float4*)&krow[4];
    float4 k2 = *(const float4*)&krow[8],  k3 = *(const float4*)&krow[12];
    float dot = q0.x*k0.x + q0.y*k0.y + q0.z*k0.z + q0.w*k0.w
              + q1.x*k1.x + q1.y*k1.y + q1.z*k1.z + q1.w*k1.w
              + q2.x*k2.x + q2.y*k2.y + q2.z*k2.z + q2.w*k2.w
              + q3.x*k3.x + q3.y*k3.y + q3.z*k3.z + q3.w*k3.w;
    const float* kpp = kpp_base + h * 12;
    float4 p0 = *(float4*)&sp[h*12+0], p1 = *(float4*)&sp[h*12+4], p2 = *(float4*)&sp[h*12+8];
    float4 c0 = *(const float4*)&kpp[0], c1 = *(const float4*)&kpp[4], c2 = *(const float4*)&kpp[8];
    float d, d2 = 0.f;
    d = p0.x-c0.x; d2 += d*d;  d = p0.y-c0.y; d2 += d*d;
    d = p0.z-c0.z; d2 += d*d;  d = p0.w-c0.w; d2 += d*d;
    d = p1.x-c1.x; d2 += d*d;  d = p1.y-c1.y; d2 += d*d;
    d = p1.z-c1.z; d2 += d*d;  d = p1.w-c1.w; d2 += d*d;
    d = p2.x-c2.x; d2 += d*d;  d = p2.y-c2.y; d2 += d*d;
    d = p2.z-c2.z; d2 += d*d;  d = p2.w-c2.w; d2 += d*d;
    float bbv = bb_base[h * LSEQ];
    lg[h] = WL_CONST * (dot * 0.25f + bbv - sch[h] * d2);
  }
  // block max per h
  #pragma unroll
  for (int h = 0; h < NH; h++) {
    float m = lg[h];
    #pragma unroll
    for (int off = 32; off >= 1; off >>= 1) m = fmaxf(m, __shfl_xor(m, off));
    if ((t & 63) == 0) redm[w*NH + h] = m;
  }
  __syncthreads();
  if (t < NH) {
    float m = redm[t];
    #pragma unroll
    for (int u = 1; u < 8; u++) m = fmaxf(m, redm[u*NH + t]);
    bcm[t] = m;
  }
  __syncthreads();
  float e[NH];
  #pragma unroll
  for (int h = 0; h < NH; h++) {
    e[h] = __expf(lg[h] - bcm[h]);
    float s = e[h];
    #pragma unroll
    for (int off = 32; off >= 1; off >>= 1) s += __shfl_xor(s, off);
    if ((t & 63) == 0) reds[w*NH + h] = s;
  }
  __syncthreads();
  if (t < NH) {
    float s = 0.f;
    #pragma unroll
    for (int u = 0; u < 8; u++) s += reds[u*NH + t];
    bcs[t] = 1.0f / s;
  }
  __syncthreads();
  float* aout = Aa + (long)i * NH * LSEQ + j;
  #pragma unroll
  for (int h = 0; h < NH; h++) aout[h * LSEQ] = e[h] * bcs[h];
}

// ---------------- op = a . z via scalar-uniform a loads, no LDS ----------------
// grid 512 (i), block 256 (c)
__global__ __launch_bounds__(256) void k_op2(const float* zin, const float* Aa, float* SH) {
  int i = blockIdx.x, t = threadIdx.x;
  const float* ab = Aa + (long)i * NH * LSEQ;
  const float* zrow = zin + (long)i * LSEQ * CZ + t;
  float acc[NH];
  #pragma unroll
  for (int h = 0; h < NH; h++) acc[h] = 0.f;
  for (int j = 0; j < LSEQ; j += 4) {
    float z0 = zrow[(long)(j+0) * CZ];
    float z1 = zrow[(long)(j+1) * CZ];
    float z2 = zrow[(long)(j+2) * CZ];
    float z3 = zrow[(long)(j+3) * CZ];
    #pragma unroll
    for (int h = 0; h < NH; h++) {
      // block/loop-uniform index -> scalar loads (s_load_dwordx4)
      float4 a4 = *(const float4*)&ab[h * LSEQ + j];
      acc[h] += a4.x*z0 + a4.y*z1 + a4.z*z2 + a4.w*z3;
    }
  }
  float* sh = SH + (long)i * SHID + t;
  #pragma unroll
  for (int h = 0; h < NH; h++) sh[h * 304] = acc[h];
}

// ---------------- ovp inverse transform + norm + shid fill ----------------
__global__ void k_ovp(const float* OVT, const float* R, const float* T, float* SH) {
  int idx = blockIdx.x * 256 + threadIdx.x;
  if (idx >= LSEQ * NH) return;
  int l = idx / NH, h = idx % NH;
  const float* o = OVT + ((long)(h * LSEQ + l)) * 40;
  float* sh = SH + (long)l * SHID + h * 304;
  #pragma unroll
  for (int d = 0; d < 16; d++) sh[256 + d] = o[d];
  const float* r = R + l*9;
  float t0 = T[l*3], t1 = T[l*3+1], t2 = T[l*3+2];
  #pragma unroll
  for (int v = 0; v < NV; v++) {
    float a = o[16+3*v+0] - t0, b = o[16+3*v+1] - t1, c = o[16+3*v+2] - t2;
    float x = r[0]*a + r[3]*b + r[6]*c;   // R^T
    float y = r[1]*a + r[4]*b + r[7]*c;
    float zz= r[2]*a + r[5]*b + r[8]*c;
    sh[272 + 3*v + 0] = x;
    sh[272 + 3*v + 1] = y;
    sh[272 + 3*v + 2] = zz;
    sh[296 + v] = sqrtf(x*x + y*y + zz*zz);
  }
}

// ---------------- layernorm: out = LN(res + y) * g + b ----------------
__global__ __launch_bounds__(384) void k_ln(const float* res, const float* y,
                                            const float* g, const float* b, float* out) {
  int l = blockIdx.x, t = threadIdx.x;
  __shared__ float red1[6], red2[6];
  __shared__ float mv[2];
  float x = res[(long)l * CS + t] + y[(long)l * CS + t];
  float s = x, s2 = x * x;
  #pragma unroll
  for (int off = 32; off >= 1; off >>= 1) { s += __shfl_xor(s, off); s2 += __shfl_xor(s2, off); }
  if ((t & 63) == 0) { red1[t >> 6] = s; red2[t >> 6] = s2; }
  __syncthreads();
  if (t == 0) {
    float ss = 0.f, ss2 = 0.f;
    #pragma unroll
    for (int u = 0; u < 6; u++) { ss += red1[u]; ss2 += red2[u]; }
    float m = ss / CS;
    float var = ss2 / CS - m * m;
    mv[0] = m; mv[1] = 1.0f / sqrtf(var + 1e-5f);
  }
  __syncthreads();
  out[(long)l * CS + t] = (x - mv[0]) * mv[1] * g[t] + b[t];
}

// ---------------- launcher ----------------
extern "C" void kernel_launch(void* const* d_in, const int* in_sizes, int n_in,
                              void* d_out, int out_size, void* d_ws, size_t ws_size,
                              hipStream_t stream) {
  const float* s    = (const float*)d_in[0];
  const float* z    = (const float*)d_in[1];
  const float* quat = (const float*)d_in[2];
  const float* trsl = (const float*)d_in[3];
  const float* Wq   = (const float*)d_in[4];
  const float* Wk   = (const float*)d_in[5];
  const float* Wv   = (const float*)d_in[6];
  const float* Wqp  = (const float*)d_in[7];
  const float* Wkp  = (const float*)d_in[8];
  const float* Wvp  = (const float*)d_in[9];
  const float* Wb   = (const float*)d_in[10];
  const float* Ws   = (const float*)d_in[11];
  const float* bs   = (const float*)d_in[12];
  const float* scale= (const float*)d_in[13];
  const float* g1   = (const float*)d_in[14];
  const float* b1   = (const float*)d_in[15];
  const float* Wm1  = (const float*)d_in[16];
  const float* bm1  = (const float*)d_in[17];
  const float* Wm2  = (const float*)d_in[18];
  const float* bm2  = (const float*)d_in[19];
  const float* Wm3  = (const float*)d_in[20];
  const float* bm3  = (const float*)d_in[21];
  const float* g2   = (const float*)d_in[22];
  const float* b2   = (const float*)d_in[23];
  float* out = (float*)d_out;

  float* p = (float*)d_ws;
  float* R    = p; p += 512*9;
  float* T    = p; p += 512*3;
  float* CH   = p; p += 16;
  unsigned short* WBP = (unsigned short*)p; p += (CZ*16)/2;  // 4096 u16 = 2048 floats
  float* Wcat = p; p += (long)CS*NALL;
  float* P    = p; p += (long)LSEQ*NALL;
  float* QPP  = p; p += LSEQ*144;
  float* KPP  = p; p += LSEQ*144;
  float* VB   = p; p += (long)NH*LSEQ*40;
  float* Bb   = p; p += (long)LSEQ*NH*LSEQ;   // also holds a (in-place softmax)
  float* OVT  = p; p += (long)NH*LSEQ*40;
  float* SH   = p; p += (long)LSEQ*SHID;
  float* T1   = p; p += LSEQ*CS;
  float* S1   = p; p += LSEQ*CS;
  float* H1   = p; p += LSEQ*CS;
  float* H2   = p; p += LSEQ*CS;
  float* H3   = p; p += LSEQ*CS;
  float* Aa   = Bb;

  k_prep<<<1, 512, 0, stream>>>(quat, trsl, scale, Wb, R, T, CH, WBP);
  k_concat<<<(CS*NALL + 255)/256, 256, 0, stream>>>(Wq, Wk, Wv, Wqp, Wkp, Wvp, Wcat);
  // P = s @ Wcat
  k_gemm<<<dim3(NALL/64, LSEQ/64, 1), 256, 0, stream>>>(
      s, Wcat, P, nullptr, LSEQ, NALL, CS, CS, NALL, NALL, 0, 0, 0, 1, 0);
  k_trans<<<(LSEQ*NH + 255)/256, 256, 0, stream>>>(P, R, T, QPP, KPP, VB);
  k_bias_mfma<<<dim3(LSEQ, 4), 256, 0, stream>>>(z, WBP, Bb);
  k_attn2<<<LSEQ, 512, 0, stream>>>(P, QPP, KPP, Bb, CH, Aa);
  k_op2<<<LSEQ, 256, 0, stream>>>(z, Aa, SH);
  // OVT[h] = a[:,h,:] @ VB[h]   (batched over h)
  k_gemm<<<dim3(1, LSEQ/64, NH), 256, 0, stream>>>(
      Aa, VB, OVT, nullptr, LSEQ, 40, LSEQ,
      NH*LSEQ, 40, 40, 512, (long)LSEQ*40, (long)LSEQ*40, 1, 0);
  k_ovp<<<(LSEQ*NH + 255)/256, 256, 0, stream>>>(OVT, R, T, SH);
  // T1 = SH @ Ws + bs   (split-K=6, atomic accumulate)
  hipMemsetAsync(T1, 0, (size_t)LSEQ*CS*sizeof(float), stream);
  k_gemm<<<dim3(CS/64, LSEQ/64, 6), 256, 0, stream>>>(
      SH, Ws, T1, bs, LSEQ, CS, SHID, SHID, CS, CS, 0, 0, 0, 6, 0);
  k_ln<<<LSEQ, CS, 0, stream>>>(s, T1, g1, b1, S1);
  k_gemm<<<dim3(CS/64, LSEQ/64, 1), 256, 0, stream>>>(
      S1, Wm1, H1, bm1, LSEQ, CS, CS, CS, CS, CS, 0, 0, 0, 1, 1);
  k_gemm<<<dim3(CS/64, LSEQ/64, 1), 256, 0, stream>>>(
      H1, Wm2, H2, bm2, LSEQ, CS, CS, CS, CS, CS, 0, 0, 0, 1, 1);
  k_gemm<<<dim3(CS/64, LSEQ/64, 1), 256, 0, stream>>>(
      H2, Wm3, H3, bm3, LSEQ, CS, CS, CS, CS, CS, 0, 0, 0, 1, 0);
  k_ln<<<LSEQ, CS, 0, stream>>>(S1, H3, g2, b2, out);
}

// Round 3
// 789.273 us; speedup vs baseline: 1.2776x; 1.2776x over previous
//
#include <hip/hip_runtime.h>
#include <math.h>

#define LSEQ 512
#define CS 384
#define CZ 256
#define HD 16
#define NH 12
#define NQ 4
#define NV 8
#define NALL 1152   // 192*3 + 144*2 + 288
#define SHID 3648   // NH * 304
// column offsets inside P rows
#define OFF_Q 0
#define OFF_K 192
#define OFF_V 384
#define OFF_QP 576
#define OFF_KP 720
#define OFF_VP 864

#define WC_CONST 0.2357022603955158f  // sqrt(2/(9*4))
#define WL_CONST 0.5773502691896258f  // sqrt(1/3)

typedef __attribute__((ext_vector_type(8))) short bf16x8;
typedef __attribute__((ext_vector_type(4))) float f32x4;

__device__ __forceinline__ short f2bf(float f) {
  unsigned u = __builtin_bit_cast(unsigned, f);
  unsigned r = (u + 0x7FFF + ((u >> 16) & 1)) >> 16;
  return (short)r;
}

// ---------------- prep: R, t, c_h, padded bf16 Wb ----------------
__global__ void k_prep(const float* quat, const float* trsl, const float* scale,
                       const float* Wb, float* R, float* T, float* CH,
                       unsigned short* WBP) {
  int t = threadIdx.x;
  if (t < LSEQ) {
    float w = quat[t*4+0], x = quat[t*4+1], y = quat[t*4+2], z = quat[t*4+3];
    float inv = 1.0f / sqrtf(w*w + x*x + y*y + z*z);
    w *= inv; x *= inv; y *= inv; z *= inv;
    float* r = R + t*9;
    r[0] = 1.f - 2.f*(y*y + z*z); r[1] = 2.f*(x*y - w*z);       r[2] = 2.f*(x*z + w*y);
    r[3] = 2.f*(x*y + w*z);       r[4] = 1.f - 2.f*(x*x + z*z); r[5] = 2.f*(y*z - w*x);
    r[6] = 2.f*(x*z - w*y);       r[7] = 2.f*(y*z + w*x);       r[8] = 1.f - 2.f*(x*x + y*y);
    T[t*3+0] = trsl[t*3+0]; T[t*3+1] = trsl[t*3+1]; T[t*3+2] = trsl[t*3+2];
  }
  if (t < NH) {
    float sc = scale[t];
    float sp = (sc > 20.f) ? sc : logf(1.f + expf(sc));
    CH[t] = 0.5f * WC_CONST * sp;
  }
  if (t < CZ) {
    #pragma unroll
    for (int h = 0; h < 16; h++)
      WBP[t*16 + h] = (h < NH) ? (unsigned short)f2bf(Wb[t*NH + h]) : (unsigned short)0;
  }
}

// ---------------- concat weights ----------------
__global__ void k_concat(const float* Wq, const float* Wk, const float* Wv,
                         const float* Wqp, const float* Wkp, const float* Wvp,
                         float* Wcat) {
  int idx = blockIdx.x * 256 + threadIdx.x;
  if (idx >= CS * NALL) return;
  int r = idx / NALL, c = idx % NALL;
  float v;
  if (c < 192)       v = Wq [r*192 + c];
  else if (c < 384)  v = Wk [r*192 + (c-192)];
  else if (c < 576)  v = Wv [r*192 + (c-384)];
  else if (c < 720)  v = Wqp[r*144 + (c-576)];
  else if (c < 864)  v = Wkp[r*144 + (c-720)];
  else               v = Wvp[r*288 + (c-864)];
  Wcat[idx] = v;
}

// ---------------- generic f32 GEMM: C = A@B (+bias), split-K via atomics ----------------
// reluA: apply relu to A elements on load (for fusing relu of the previous layer)
__global__ __launch_bounds__(256) void k_gemm(
    const float* A, const float* B, float* C, const float* bias,
    int M, int N, int K, int lda, int ldb, int ldc,
    long strideA, long strideB, long strideC,
    int splitk, int relu, int reluA) {
  int zb = blockIdx.z;
  int batch = zb / splitk, ks = zb % splitk;
  A += (long)batch * strideA;
  B += (long)batch * strideB;
  C += (long)batch * strideC;
  int Ksub = K / splitk;
  int kbeg = ks * Ksub;

  __shared__ __align__(16) float As[16][68];
  __shared__ __align__(16) float Bs[16][68];
  int t = threadIdx.x;
  int m0 = blockIdx.y * 64, n0 = blockIdx.x * 64;
  int arow = t >> 2,  akq = (t & 3) * 4;
  int bkk  = t >> 4,  bnq = (t & 15) * 4;
  int ty = (t >> 4) * 4, tx = (t & 15) * 4;
  float acc[4][4];
  #pragma unroll
  for (int r = 0; r < 4; r++)
    #pragma unroll
    for (int c = 0; c < 4; c++) acc[r][c] = 0.f;

  for (int kb = kbeg; kb < kbeg + Ksub; kb += 16) {
    float4 av = *(const float4*)&A[(long)(m0 + arow) * lda + kb + akq];
    if (reluA) {
      av.x = fmaxf(av.x, 0.f); av.y = fmaxf(av.y, 0.f);
      av.z = fmaxf(av.z, 0.f); av.w = fmaxf(av.w, 0.f);
    }
    float4 bv;
    const float* brow = B + (long)(kb + bkk) * ldb;
    if (n0 + bnq + 3 < N) {
      bv = *(const float4*)&brow[n0 + bnq];
    } else {
      float tmp[4];
      #pragma unroll
      for (int u = 0; u < 4; u++) tmp[u] = (n0 + bnq + u < N) ? brow[n0 + bnq + u] : 0.f;
      bv = make_float4(tmp[0], tmp[1], tmp[2], tmp[3]);
    }
    __syncthreads();
    As[akq+0][arow] = av.x; As[akq+1][arow] = av.y;
    As[akq+2][arow] = av.z; As[akq+3][arow] = av.w;
    *(float4*)&Bs[bkk][bnq] = bv;
    __syncthreads();
    #pragma unroll
    for (int kk = 0; kk < 16; kk++) {
      float4 a4 = *(float4*)&As[kk][ty];
      float4 b4 = *(float4*)&Bs[kk][tx];
      acc[0][0] += a4.x*b4.x; acc[0][1] += a4.x*b4.y; acc[0][2] += a4.x*b4.z; acc[0][3] += a4.x*b4.w;
      acc[1][0] += a4.y*b4.x; acc[1][1] += a4.y*b4.y; acc[1][2] += a4.y*b4.z; acc[1][3] += a4.y*b4.w;
      acc[2][0] += a4.z*b4.x; acc[2][1] += a4.z*b4.y; acc[2][2] += a4.z*b4.z; acc[2][3] += a4.z*b4.w;
      acc[3][0] += a4.w*b4.x; acc[3][1] += a4.w*b4.y; acc[3][2] += a4.w*b4.z; acc[3][3] += a4.w*b4.w;
    }
  }

  if (splitk == 1) {
    #pragma unroll
    for (int r = 0; r < 4; r++) {
      int m = m0 + ty + r;
      #pragma unroll
      for (int c = 0; c < 4; c++) {
        int n = n0 + tx + c;
        if (n < N) {
          float v = acc[r][c] + (bias ? bias[n] : 0.f);
          if (relu) v = fmaxf(v, 0.f);
          C[(long)m * ldc + n] = v;
        }
      }
    }
  } else {
    #pragma unroll
    for (int r = 0; r < 4; r++) {
      int m = m0 + ty + r;
      #pragma unroll
      for (int c = 0; c < 4; c++) {
        int n = n0 + tx + c;
        if (n < N) {
          float v = acc[r][c] + ((ks == 0 && bias) ? bias[n] : 0.f);
          atomicAdd(&C[(long)m * ldc + n], v);
        }
      }
    }
  }
}

// ---------------- rigid transforms: QPP, KT (transposed), KPT (transposed), VB ----------------
// grid 24 x 256; thread = (h, l) with l fastest -> coalesced transposed writes
__global__ void k_trans(const float* P, const float* R, const float* T,
                        float* QPP, float* KT, float* KPT, float* VB) {
  int idx = blockIdx.x * 256 + threadIdx.x;
  if (idx >= LSEQ * NH) return;
  int h = idx / LSEQ, l = idx % LSEQ;
  const float* r = R + l*9;
  float t0 = T[l*3], t1 = T[l*3+1], t2 = T[l*3+2];
  const float* prow = P + (long)l * NALL;
  // qpp (h-major layout per l, for scalar reads in attn)
  #pragma unroll
  for (int pq = 0; pq < NQ; pq++) {
    const float* x = prow + OFF_QP + h*12 + pq*3;
    float a = x[0], b = x[1], c = x[2];
    float* o = QPP + l*144 + h*12 + pq*3;
    o[0] = r[0]*a + r[1]*b + r[2]*c + t0;
    o[1] = r[3]*a + r[4]*b + r[5]*c + t1;
    o[2] = r[6]*a + r[7]*b + r[8]*c + t2;
  }
  // K transposed: KT[h][d][l]
  #pragma unroll
  for (int d = 0; d < HD; d++)
    KT[(h*HD + d)*LSEQ + l] = prow[OFF_K + h*HD + d];
  // kpp transposed: KPT[h][p][l]
  #pragma unroll
  for (int pq = 0; pq < NQ; pq++) {
    const float* x = prow + OFF_KP + h*12 + pq*3;
    float a = x[0], b = x[1], c = x[2];
    KPT[(h*12 + pq*3 + 0)*LSEQ + l] = r[0]*a + r[1]*b + r[2]*c + t0;
    KPT[(h*12 + pq*3 + 1)*LSEQ + l] = r[3]*a + r[4]*b + r[5]*c + t1;
    KPT[(h*12 + pq*3 + 2)*LSEQ + l] = r[6]*a + r[7]*b + r[8]*c + t2;
  }
  // VB = [v | vpp]
  float* vb = VB + ((long)(h * LSEQ + l)) * 40;
  #pragma unroll
  for (int d = 0; d < 16; d++) vb[d] = prow[OFF_V + h*16 + d];
  #pragma unroll
  for (int pv = 0; pv < NV; pv++) {
    const float* x = prow + OFF_VP + h*24 + pv*3;
    float a = x[0], b = x[1], c = x[2];
    vb[16 + 3*pv + 0] = r[0]*a + r[1]*b + r[2]*c + t0;
    vb[16 + 3*pv + 1] = r[3]*a + r[4]*b + r[5]*c + t1;
    vb[16 + 3*pv + 2] = r[6]*a + r[7]*b + r[8]*c + t2;
  }
}

// ---------------- b = z @ Wb via MFMA bf16, no LDS ----------------
__global__ __launch_bounds__(256) void k_bias_mfma(const float* zin,
    const unsigned short* WBP, float* Bb) {
  int i = blockIdx.x;
  int part = blockIdx.y;
  int t = threadIdx.x;
  int w = t >> 6, l = t & 63;
  int r = l & 15, kg = l >> 4;

  bf16x8 bfrag[8];
  #pragma unroll
  for (int kt = 0; kt < 8; kt++) {
    #pragma unroll
    for (int jj = 0; jj < 8; jj++) {
      int c = kt*32 + kg*8 + jj;
      bfrag[kt][jj] = (short)WBP[c*16 + r];
    }
  }

  #pragma unroll
  for (int tt = 0; tt < 2; tt++) {
    int j0 = part*128 + (w*2 + tt)*16;
    const float* zrow = zin + ((long)i*LSEQ + j0 + r) * CZ + kg*8;
    f32x4 acc = {0.f, 0.f, 0.f, 0.f};
    #pragma unroll
    for (int kt = 0; kt < 8; kt++) {
      float4 z0 = *(const float4*)(zrow + kt*32);
      float4 z1 = *(const float4*)(zrow + kt*32 + 4);
      bf16x8 af;
      af[0] = f2bf(z0.x); af[1] = f2bf(z0.y); af[2] = f2bf(z0.z); af[3] = f2bf(z0.w);
      af[4] = f2bf(z1.x); af[5] = f2bf(z1.y); af[6] = f2bf(z1.z); af[7] = f2bf(z1.w);
      acc = __builtin_amdgcn_mfma_f32_16x16x32_bf16(af, bfrag[kt], acc, 0, 0, 0);
    }
    if (r < NH) {
      int jbase = j0 + kg*4;
      float4 o = make_float4(acc[0], acc[1], acc[2], acc[3]);
      *(float4*)&Bb[((long)i*NH + r)*LSEQ + jbase] = o;
    }
  }
}

// ---------------- attention: coalesced transposed reads, 2 i-rows/block ----------------
// grid 256, block 512 (thread = j). Softmax without max-subtraction (logits bounded).
#define AI 2
__global__ __launch_bounds__(512) void k_attn3(const float* P, const float* QPP,
    const float* KT, const float* KPT, const float* Bb, const float* CH, float* Aa) {
  int i0 = blockIdx.x * AI;
  int t = threadIdx.x, w = t >> 6, j = t;
  __shared__ float reds[2][8][AI];
  __shared__ float bcs[2][AI];
  float lg[AI];
  for (int h = 0; h < NH; h++) {
    int pb = h & 1;
    float kreg[16];
    #pragma unroll
    for (int d = 0; d < 16; d++) kreg[d] = KT[(h*16 + d)*LSEQ + j];
    float kp[12];
    #pragma unroll
    for (int p = 0; p < 12; p++) kp[p] = KPT[(h*12 + p)*LSEQ + j];
    float ch = CH[h];
    #pragma unroll
    for (int ii = 0; ii < AI; ii++) {
      const float* q  = P + (long)(i0+ii)*NALL + OFF_Q + h*HD;   // uniform -> s_load
      const float* qp = QPP + (i0+ii)*144 + h*12;                // uniform -> s_load
      float dot = 0.f;
      #pragma unroll
      for (int d = 0; d < 16; d++) dot += q[d] * kreg[d];
      float d2 = 0.f;
      #pragma unroll
      for (int p = 0; p < 12; p++) { float dd = qp[p] - kp[p]; d2 += dd*dd; }
      float bb = Bb[((long)(i0+ii)*NH + h)*LSEQ + j];
      lg[ii] = __expf(WL_CONST * (0.25f*dot + bb - ch*d2));
    }
    #pragma unroll
    for (int ii = 0; ii < AI; ii++) {
      float sv = lg[ii];
      #pragma unroll
      for (int off = 32; off >= 1; off >>= 1) sv += __shfl_xor(sv, off);
      if ((t & 63) == 0) reds[pb][w][ii] = sv;
    }
    __syncthreads();
    if (t < AI) {
      float sv = 0.f;
      #pragma unroll
      for (int u = 0; u < 8; u++) sv += reds[pb][u][t];
      bcs[pb][t] = 1.0f / sv;
    }
    __syncthreads();
    #pragma unroll
    for (int ii = 0; ii < AI; ii++)
      Aa[((long)(i0+ii)*NH + h)*LSEQ + j] = lg[ii] * bcs[pb][ii];
    // no trailing barrier: next h uses the other parity buffer
  }
}

// ---------------- op = a . z via scalar-uniform a loads ----------------
__global__ __launch_bounds__(256) void k_op2(const float* zin, const float* Aa, float* SH) {
  int i = blockIdx.x, t = threadIdx.x;
  const float* ab = Aa + (long)i * NH * LSEQ;
  const float* zrow = zin + (long)i * LSEQ * CZ + t;
  float acc[NH];
  #pragma unroll
  for (int h = 0; h < NH; h++) acc[h] = 0.f;
  for (int j = 0; j < LSEQ; j += 4) {
    float z0 = zrow[(long)(j+0) * CZ];
    float z1 = zrow[(long)(j+1) * CZ];
    float z2 = zrow[(long)(j+2) * CZ];
    float z3 = zrow[(long)(j+3) * CZ];
    #pragma unroll
    for (int h = 0; h < NH; h++) {
      float4 a4 = *(const float4*)&ab[h * LSEQ + j];
      acc[h] += a4.x*z0 + a4.y*z1 + a4.z*z2 + a4.w*z3;
    }
  }
  float* sh = SH + (long)i * SHID + t;
  #pragma unroll
  for (int h = 0; h < NH; h++) sh[h * 304] = acc[h];
}

// ---------------- ovp inverse transform + norm + shid fill ----------------
__global__ void k_ovp(const float* OVT, const float* R, const float* T, float* SH) {
  int idx = blockIdx.x * 256 + threadIdx.x;
  if (idx >= LSEQ * NH) return;
  int l = idx / NH, h = idx % NH;
  const float* o = OVT + ((long)(h * LSEQ + l)) * 40;
  float* sh = SH + (long)l * SHID + h * 304;
  #pragma unroll
  for (int d = 0; d < 16; d++) sh[256 + d] = o[d];
  const float* r = R + l*9;
  float t0 = T[l*3], t1 = T[l*3+1], t2 = T[l*3+2];
  #pragma unroll
  for (int v = 0; v < NV; v++) {
    float a = o[16+3*v+0] - t0, b = o[16+3*v+1] - t1, c = o[16+3*v+2] - t2;
    float x = r[0]*a + r[3]*b + r[6]*c;   // R^T
    float y = r[1]*a + r[4]*b + r[7]*c;
    float zz= r[2]*a + r[5]*b + r[8]*c;
    sh[272 + 3*v + 0] = x;
    sh[272 + 3*v + 1] = y;
    sh[272 + 3*v + 2] = zz;
    sh[296 + v] = sqrtf(x*x + y*y + zz*zz);
  }
}

// ---------------- layernorm: out = LN(res + y) * g + b ----------------
__global__ __launch_bounds__(384) void k_ln(const float* res, const float* y,
                                            const float* g, const float* b, float* out) {
  int l = blockIdx.x, t = threadIdx.x;
  __shared__ float red1[6], red2[6];
  __shared__ float mv[2];
  float x = res[(long)l * CS + t] + y[(long)l * CS + t];
  float s = x, s2 = x * x;
  #pragma unroll
  for (int off = 32; off >= 1; off >>= 1) { s += __shfl_xor(s, off); s2 += __shfl_xor(s2, off); }
  if ((t & 63) == 0) { red1[t >> 6] = s; red2[t >> 6] = s2; }
  __syncthreads();
  if (t == 0) {
    float ss = 0.f, ss2 = 0.f;
    #pragma unroll
    for (int u = 0; u < 6; u++) { ss += red1[u]; ss2 += red2[u]; }
    float m = ss / CS;
    float var = ss2 / CS - m * m;
    mv[0] = m; mv[1] = 1.0f / sqrtf(var + 1e-5f);
  }
  __syncthreads();
  out[(long)l * CS + t] = (x - mv[0]) * mv[1] * g[t] + b[t];
}

// ---------------- launcher ----------------
extern "C" void kernel_launch(void* const* d_in, const int* in_sizes, int n_in,
                              void* d_out, int out_size, void* d_ws, size_t ws_size,
                              hipStream_t stream) {
  const float* s    = (const float*)d_in[0];
  const float* z    = (const float*)d_in[1];
  const float* quat = (const float*)d_in[2];
  const float* trsl = (const float*)d_in[3];
  const float* Wq   = (const float*)d_in[4];
  const float* Wk   = (const float*)d_in[5];
  const float* Wv   = (const float*)d_in[6];
  const float* Wqp  = (const float*)d_in[7];
  const float* Wkp  = (const float*)d_in[8];
  const float* Wvp  = (const float*)d_in[9];
  const float* Wb   = (const float*)d_in[10];
  const float* Ws   = (const float*)d_in[11];
  const float* bs   = (const float*)d_in[12];
  const float* scale= (const float*)d_in[13];
  const float* g1   = (const float*)d_in[14];
  const float* b1   = (const float*)d_in[15];
  const float* Wm1  = (const float*)d_in[16];
  const float* bm1  = (const float*)d_in[17];
  const float* Wm2  = (const float*)d_in[18];
  const float* bm2  = (const float*)d_in[19];
  const float* Wm3  = (const float*)d_in[20];
  const float* bm3  = (const float*)d_in[21];
  const float* g2   = (const float*)d_in[22];
  const float* b2   = (const float*)d_in[23];
  float* out = (float*)d_out;

  float* p = (float*)d_ws;
  float* R    = p; p += 512*9;
  float* T    = p; p += 512*3;
  float* CH   = p; p += 16;
  unsigned short* WBP = (unsigned short*)p; p += (CZ*16)/2;
  float* Wcat = p; p += (long)CS*NALL;
  float* P    = p; p += (long)LSEQ*NALL;
  float* QPP  = p; p += LSEQ*144;
  float* KT   = p; p += NH*HD*LSEQ;     // 98304
  float* KPT  = p; p += NH*12*LSEQ;     // 73728
  float* VB   = p; p += (long)NH*LSEQ*40;
  float* Bb   = p; p += (long)LSEQ*NH*LSEQ;   // also holds a (in-place softmax)
  float* OVT  = p; p += (long)NH*LSEQ*40;
  float* SH   = p; p += (long)LSEQ*SHID;
  float* T1   = p; p += LSEQ*CS;
  float* S1   = p; p += LSEQ*CS;
  float* H1   = p; p += LSEQ*CS;
  float* H2   = p; p += LSEQ*CS;
  float* H3   = p; p += LSEQ*CS;
  float* Aa   = Bb;

  k_prep<<<1, 512, 0, stream>>>(quat, trsl, scale, Wb, R, T, CH, WBP);
  k_concat<<<(CS*NALL + 255)/256, 256, 0, stream>>>(Wq, Wk, Wv, Wqp, Wkp, Wvp, Wcat);
  // P = s @ Wcat
  k_gemm<<<dim3(NALL/64, LSEQ/64, 1), 256, 0, stream>>>(
      s, Wcat, P, nullptr, LSEQ, NALL, CS, CS, NALL, NALL, 0, 0, 0, 1, 0, 0);
  k_trans<<<(LSEQ*NH + 255)/256, 256, 0, stream>>>(P, R, T, QPP, KT, KPT, VB);
  k_bias_mfma<<<dim3(LSEQ, 4), 256, 0, stream>>>(z, WBP, Bb);
  k_attn3<<<LSEQ/AI, 512, 0, stream>>>(P, QPP, KT, KPT, Bb, CH, Aa);
  k_op2<<<LSEQ, 256, 0, stream>>>(z, Aa, SH);
  // OVT[h] = a[:,h,:] @ VB[h]   (batched over h)
  k_gemm<<<dim3(1, LSEQ/64, NH), 256, 0, stream>>>(
      Aa, VB, OVT, nullptr, LSEQ, 40, LSEQ,
      NH*LSEQ, 40, 40, 512, (long)LSEQ*40, (long)LSEQ*40, 1, 0, 0);
  k_ovp<<<(LSEQ*NH + 255)/256, 256, 0, stream>>>(OVT, R, T, SH);
  // T1 = SH @ Ws + bs   (split-K=6, atomic accumulate)
  hipMemsetAsync(T1, 0, (size_t)LSEQ*CS*sizeof(float), stream);
  hipMemsetAsync(H1, 0, (size_t)LSEQ*CS*sizeof(float), stream);
  hipMemsetAsync(H2, 0, (size_t)LSEQ*CS*sizeof(float), stream);
  hipMemsetAsync(H3, 0, (size_t)LSEQ*CS*sizeof(float), stream);
  k_gemm<<<dim3(CS/64, LSEQ/64, 6), 256, 0, stream>>>(
      SH, Ws, T1, bs, LSEQ, CS, SHID, SHID, CS, CS, 0, 0, 0, 6, 0, 0);
  k_ln<<<LSEQ, CS, 0, stream>>>(s, T1, g1, b1, S1);
  // MLP: split-K=4, relu fused into next GEMM's A-read
  k_gemm<<<dim3(CS/64, LSEQ/64, 4), 256, 0, stream>>>(
      S1, Wm1, H1, bm1, LSEQ, CS, CS, CS, CS, CS, 0, 0, 0, 4, 0, 0);
  k_gemm<<<dim3(CS/64, LSEQ/64, 4), 256, 0, stream>>>(
      H1, Wm2, H2, bm2, LSEQ, CS, CS, CS, CS, CS, 0, 0, 0, 4, 0, 1);
  k_gemm<<<dim3(CS/64, LSEQ/64, 4), 256, 0, stream>>>(
      H2, Wm3, H3, bm3, LSEQ, CS, CS, CS, CS, CS, 0, 0, 0, 4, 0, 1);
  k_ln<<<LSEQ, CS, 0, stream>>>(S1, H3, g2, b2, out);
}

// Round 4
// 689.226 us; speedup vs baseline: 1.4630x; 1.1452x over previous
//
#include <hip/hip_runtime.h>
#include <math.h>

#define LSEQ 512
#define CS 384
#define CZ 256
#define HD 16
#define NH 12
#define NQ 4
#define NV 8
#define NALL 1152   // 192*3 + 144*2 + 288
#define SHID 3648   // NH * 304
#define OFF_Q 0
#define OFF_K 192
#define OFF_V 384
#define OFF_QP 576
#define OFF_KP 720
#define OFF_VP 864

#define WC_CONST 0.2357022603955158f  // sqrt(2/(9*4))
#define WL_CONST 0.5773502691896258f  // sqrt(1/3)

typedef __attribute__((ext_vector_type(8))) short bf16x8;
typedef __attribute__((ext_vector_type(4))) float f32x4;

__device__ __forceinline__ short f2bf(float f) {
  unsigned u = __builtin_bit_cast(unsigned, f);
  unsigned r = (u + 0x7FFF + ((u >> 16) & 1)) >> 16;
  return (short)r;
}

// ---------------- prep: R, t, c_h, padded bf16 Wb ----------------
__global__ void k_prep(const float* quat, const float* trsl, const float* scale,
                       const float* Wb, float* R, float* T, float* CH,
                       unsigned short* WBP) {
  int t = threadIdx.x;
  if (t < LSEQ) {
    float w = quat[t*4+0], x = quat[t*4+1], y = quat[t*4+2], z = quat[t*4+3];
    float inv = 1.0f / sqrtf(w*w + x*x + y*y + z*z);
    w *= inv; x *= inv; y *= inv; z *= inv;
    float* r = R + t*9;
    r[0] = 1.f - 2.f*(y*y + z*z); r[1] = 2.f*(x*y - w*z);       r[2] = 2.f*(x*z + w*y);
    r[3] = 2.f*(x*y + w*z);       r[4] = 1.f - 2.f*(x*x + z*z); r[5] = 2.f*(y*z - w*x);
    r[6] = 2.f*(x*z - w*y);       r[7] = 2.f*(y*z + w*x);       r[8] = 1.f - 2.f*(x*x + y*y);
    T[t*3+0] = trsl[t*3+0]; T[t*3+1] = trsl[t*3+1]; T[t*3+2] = trsl[t*3+2];
  }
  if (t < NH) {
    float sc = scale[t];
    float sp = (sc > 20.f) ? sc : logf(1.f + expf(sc));
    CH[t] = 0.5f * WC_CONST * sp;
  }
  if (t < CZ) {
    #pragma unroll
    for (int h = 0; h < 16; h++)
      WBP[t*16 + h] = (h < NH) ? (unsigned short)f2bf(Wb[t*NH + h]) : (unsigned short)0;
  }
}

// ---------------- concat weights ----------------
__global__ void k_concat(const float* Wq, const float* Wk, const float* Wv,
                         const float* Wqp, const float* Wkp, const float* Wvp,
                         float* Wcat) {
  int idx = blockIdx.x * 256 + threadIdx.x;
  if (idx >= CS * NALL) return;
  int r = idx / NALL, c = idx % NALL;
  float v;
  if (c < 192)       v = Wq [r*192 + c];
  else if (c < 384)  v = Wk [r*192 + (c-192)];
  else if (c < 576)  v = Wv [r*192 + (c-384)];
  else if (c < 720)  v = Wqp[r*144 + (c-576)];
  else if (c < 864)  v = Wkp[r*144 + (c-720)];
  else               v = Wvp[r*288 + (c-864)];
  Wcat[idx] = v;
}

// ---------------- f32 GEMM with register prefetch; N,M multiples of 64 ----------------
// grid (N/64, M/64, splitk). splitk>1 accumulates via atomics into zeroed C.
__global__ __launch_bounds__(256) void k_gemm(
    const float* A, const float* B, float* C, const float* bias,
    int K, int lda, int ldb, int ldc, int splitk, int relu, int reluA) {
  int ks = blockIdx.z;
  int Ksub = K / splitk;
  int kbeg = ks * Ksub, kend = kbeg + Ksub;

  __shared__ __align__(16) float As[16][68];
  __shared__ __align__(16) float Bs[16][68];
  int t = threadIdx.x;
  int m0 = blockIdx.y * 64, n0 = blockIdx.x * 64;
  int arow = t >> 2,  akq = (t & 3) * 4;
  int bkk  = t >> 4,  bnq = (t & 15) * 4;
  int ty = (t >> 4) * 4, tx = (t & 15) * 4;
  float acc[4][4];
  #pragma unroll
  for (int r = 0; r < 4; r++)
    #pragma unroll
    for (int c = 0; c < 4; c++) acc[r][c] = 0.f;

  const float* aptr  = A + (long)(m0 + arow) * lda + akq;
  const float* bbase = B + n0 + bnq;
  float4 av = *(const float4*)&aptr[kbeg];
  float4 bv = *(const float4*)&bbase[(long)(kbeg + bkk) * ldb];

  for (int kb = kbeg; kb < kend; kb += 16) {
    float4 a_cur = av, b_cur = bv;
    if (reluA) {
      a_cur.x = fmaxf(a_cur.x, 0.f); a_cur.y = fmaxf(a_cur.y, 0.f);
      a_cur.z = fmaxf(a_cur.z, 0.f); a_cur.w = fmaxf(a_cur.w, 0.f);
    }
    __syncthreads();
    As[akq+0][arow] = a_cur.x; As[akq+1][arow] = a_cur.y;
    As[akq+2][arow] = a_cur.z; As[akq+3][arow] = a_cur.w;
    *(float4*)&Bs[bkk][bnq] = b_cur;
    __syncthreads();
    if (kb + 16 < kend) {
      av = *(const float4*)&aptr[kb + 16];
      bv = *(const float4*)&bbase[(long)(kb + 16 + bkk) * ldb];
    }
    #pragma unroll
    for (int kk = 0; kk < 16; kk++) {
      float4 a4 = *(float4*)&As[kk][ty];
      float4 b4 = *(float4*)&Bs[kk][tx];
      acc[0][0] += a4.x*b4.x; acc[0][1] += a4.x*b4.y; acc[0][2] += a4.x*b4.z; acc[0][3] += a4.x*b4.w;
      acc[1][0] += a4.y*b4.x; acc[1][1] += a4.y*b4.y; acc[1][2] += a4.y*b4.z; acc[1][3] += a4.y*b4.w;
      acc[2][0] += a4.z*b4.x; acc[2][1] += a4.z*b4.y; acc[2][2] += a4.z*b4.z; acc[2][3] += a4.z*b4.w;
      acc[3][0] += a4.w*b4.x; acc[3][1] += a4.w*b4.y; acc[3][2] += a4.w*b4.z; acc[3][3] += a4.w*b4.w;
    }
  }

  if (splitk == 1) {
    #pragma unroll
    for (int r = 0; r < 4; r++) {
      int m = m0 + ty + r;
      #pragma unroll
      for (int c = 0; c < 4; c++) {
        int n = n0 + tx + c;
        float v = acc[r][c] + (bias ? bias[n] : 0.f);
        if (relu) v = fmaxf(v, 0.f);
        C[(long)m * ldc + n] = v;
      }
    }
  } else {
    #pragma unroll
    for (int r = 0; r < 4; r++) {
      int m = m0 + ty + r;
      #pragma unroll
      for (int c = 0; c < 4; c++) {
        int n = n0 + tx + c;
        float v = acc[r][c] + ((ks == 0 && bias) ? bias[n] : 0.f);
        atomicAdd(&C[(long)m * ldc + n], v);
      }
    }
  }
}

// ---------------- rigid transforms, 3 concurrent tasks ----------------
// grid (24, 3) x 256; idx = (h, l) l fastest -> coalesced writes
__global__ void k_trans(const float* P, const float* R, const float* T,
                        float* QPP, float* KT, float* KPT, float* VBT) {
  int task = blockIdx.y;
  int idx = blockIdx.x * 256 + threadIdx.x;
  if (idx >= LSEQ * NH) return;
  int h = idx / LSEQ, l = idx % LSEQ;
  const float* r = R + l*9;
  float t0 = T[l*3], t1 = T[l*3+1], t2 = T[l*3+2];
  const float* prow = P + (long)l * NALL;
  if (task == 0) {
    #pragma unroll
    for (int pq = 0; pq < NQ; pq++) {
      const float* x = prow + OFF_QP + h*12 + pq*3;
      float a = x[0], b = x[1], c = x[2];
      float* o = QPP + l*144 + h*12 + pq*3;
      o[0] = r[0]*a + r[1]*b + r[2]*c + t0;
      o[1] = r[3]*a + r[4]*b + r[5]*c + t1;
      o[2] = r[6]*a + r[7]*b + r[8]*c + t2;
    }
    #pragma unroll
    for (int d = 0; d < HD; d++)
      KT[(h*HD + d)*LSEQ + l] = prow[OFF_K + h*HD + d];
  } else if (task == 1) {
    #pragma unroll
    for (int pq = 0; pq < NQ; pq++) {
      const float* x = prow + OFF_KP + h*12 + pq*3;
      float a = x[0], b = x[1], c = x[2];
      KPT[(h*12 + pq*3 + 0)*LSEQ + l] = r[0]*a + r[1]*b + r[2]*c + t0;
      KPT[(h*12 + pq*3 + 1)*LSEQ + l] = r[3]*a + r[4]*b + r[5]*c + t1;
      KPT[(h*12 + pq*3 + 2)*LSEQ + l] = r[6]*a + r[7]*b + r[8]*c + t2;
    }
  } else {
    // VBT[(h*40+p)][l] : p<16 = v, p>=16 = vpp
    #pragma unroll
    for (int d = 0; d < 16; d++)
      VBT[((long)(h*40 + d))*LSEQ + l] = prow[OFF_V + h*16 + d];
    #pragma unroll
    for (int pv = 0; pv < NV; pv++) {
      const float* x = prow + OFF_VP + h*24 + pv*3;
      float a = x[0], b = x[1], c = x[2];
      VBT[((long)(h*40 + 16 + 3*pv + 0))*LSEQ + l] = r[0]*a + r[1]*b + r[2]*c + t0;
      VBT[((long)(h*40 + 16 + 3*pv + 1))*LSEQ + l] = r[3]*a + r[4]*b + r[5]*c + t1;
      VBT[((long)(h*40 + 16 + 3*pv + 2))*LSEQ + l] = r[6]*a + r[7]*b + r[8]*c + t2;
    }
  }
}

// ---------------- logits sans bias: LG[i][h][j] = WL*(qk/4 - ch*d2) ----------------
#define AI 2
__global__ __launch_bounds__(512) void k_logit(const float* P, const float* QPP,
    const float* KT, const float* KPT, const float* CH, float* LG) {
  int i0 = blockIdx.x * AI;
  int t = threadIdx.x, j = t;
  #pragma unroll
  for (int h = 0; h < NH; h++) {
    float kreg[16];
    #pragma unroll
    for (int d = 0; d < 16; d++) kreg[d] = KT[(h*16 + d)*LSEQ + j];
    float kp[12];
    #pragma unroll
    for (int p = 0; p < 12; p++) kp[p] = KPT[(h*12 + p)*LSEQ + j];
    float ch = CH[h];
    #pragma unroll
    for (int ii = 0; ii < AI; ii++) {
      const float* q  = P + (long)(i0+ii)*NALL + OFF_Q + h*HD;   // uniform -> s_load
      const float* qp = QPP + (i0+ii)*144 + h*12;                // uniform -> s_load
      float dot = 0.f;
      #pragma unroll
      for (int d = 0; d < 16; d++) dot += q[d] * kreg[d];
      float d2 = 0.f;
      #pragma unroll
      for (int p = 0; p < 12; p++) { float dd = qp[p] - kp[p]; d2 += dd*dd; }
      LG[((long)(i0+ii)*NH + h)*LSEQ + j] = WL_CONST * (0.25f*dot - ch*d2);
    }
  }
}

// ---------------- fused bias + softmax + op + ov/ovp over a single z pass ----------------
// grid 512 (i), 256 threads (4 waves). Per 64-j tile:
//   MFMA: b = z_tile @ Wb  (bf16), e = exp(LG + WL*b) -> LDS
//   VALU: accop[c][h] += e*z (z re-read, L2-hot); accv[(h,p)] += e*VBT
// Final: divide by sum(e), write SH op-region and OVT.
__global__ __launch_bounds__(256) void k_fused(const float* zin,
    const unsigned short* WBP, const float* LG, const float* VBT,
    float* SH, float* OVT) {
  __shared__ __align__(16) float lgs[NH][520];
  __shared__ __align__(16) float es[NH][68];
  __shared__ float sred[4][NH];
  __shared__ float ssum[NH];
  int i = blockIdx.x, t = threadIdx.x;
  int w = t >> 6, l = t & 63;
  int r = l & 15, kg = l >> 4;

  // stage LG[i] (12x512) coalesced
  const float* lgsrc = LG + (long)i * NH * LSEQ;
  #pragma unroll
  for (int idx = t; idx < NH*LSEQ/4; idx += 256) {
    int h = idx >> 7, q4 = idx & 127;
    *(float4*)&lgs[h][q4*4] = *(const float4*)&lgsrc[h*LSEQ + q4*4];
  }

  // Wb B-frags (col h = r, k = kg*8+jj within kt*32 chunk)
  bf16x8 bfrag[8];
  #pragma unroll
  for (int kt = 0; kt < 8; kt++)
    #pragma unroll
    for (int jj = 0; jj < 8; jj++)
      bfrag[kt][jj] = (short)WBP[(kt*32 + kg*8 + jj)*16 + r];

  float accop[NH];
  #pragma unroll
  for (int h = 0; h < NH; h++) accop[h] = 0.f;
  int pair0 = t, pair1 = t + 256;             // (h,p) flat, 480 total
  int h0 = pair0 / 40, p0 = pair0 % 40;
  int h1 = pair1 / 40, p1 = pair1 % 40;
  float accv0 = 0.f, accv1 = 0.f;
  float sparts = 0.f;
  int hh = (r < NH) ? r : 0;

  __syncthreads();   // lgs ready

  for (int jt = 0; jt < LSEQ; jt += 64) {
    int j0 = jt + w*16;
    // ---- MFMA phase: b for rows j0..j0+15, col h=r ----
    const float* zrow = zin + ((long)i*LSEQ + j0 + r)*CZ + kg*8;
    f32x4 acc = {0.f, 0.f, 0.f, 0.f};
    #pragma unroll
    for (int kt = 0; kt < 8; kt++) {
      float4 z0 = *(const float4*)(zrow + kt*32);
      float4 z1 = *(const float4*)(zrow + kt*32 + 4);
      bf16x8 af;
      af[0] = f2bf(z0.x); af[1] = f2bf(z0.y); af[2] = f2bf(z0.z); af[3] = f2bf(z0.w);
      af[4] = f2bf(z1.x); af[5] = f2bf(z1.y); af[6] = f2bf(z1.z); af[7] = f2bf(z1.w);
      acc = __builtin_amdgcn_mfma_f32_16x16x32_bf16(af, bfrag[kt], acc, 0, 0, 0);
    }
    // e = exp(LG + WL*b); D-layout: col h=r, row j = j0 + kg*4 + reg
    float4 lgv = *(float4*)&lgs[hh][j0 + kg*4];
    float e0 = __expf(lgv.x + WL_CONST*acc[0]);
    float e1 = __expf(lgv.y + WL_CONST*acc[1]);
    float e2 = __expf(lgv.z + WL_CONST*acc[2]);
    float e3 = __expf(lgv.w + WL_CONST*acc[3]);
    if (r < NH) {
      sparts += e0 + e1 + e2 + e3;
      *(float4*)&es[r][w*16 + kg*4] = make_float4(e0, e1, e2, e3);
    }
    __syncthreads();   // es ready
    // ---- op phase: c = t, z re-read (L2-hot) ----
    const float* zc = zin + ((long)i*LSEQ + jt)*CZ + t;
    #pragma unroll 4
    for (int jj = 0; jj < 64; jj += 4) {
      float z0 = zc[(jj+0)*CZ], z1 = zc[(jj+1)*CZ];
      float z2 = zc[(jj+2)*CZ], z3 = zc[(jj+3)*CZ];
      #pragma unroll
      for (int h = 0; h < NH; h++) {
        float4 ev = *(float4*)&es[h][jj];
        accop[h] += ev.x*z0 + ev.y*z1 + ev.z*z2 + ev.w*z3;
      }
    }
    // ---- ovt phase ----
    {
      const float* vb0 = VBT + ((long)pair0)*LSEQ + jt;
      #pragma unroll
      for (int jj = 0; jj < 64; jj += 4) {
        float4 vv = *(const float4*)&vb0[jj];
        float4 ev = *(float4*)&es[h0][jj];
        accv0 += vv.x*ev.x + vv.y*ev.y + vv.z*ev.z + vv.w*ev.w;
      }
      if (pair1 < 480) {
        const float* vb1 = VBT + ((long)pair1)*LSEQ + jt;
        #pragma unroll
        for (int jj = 0; jj < 64; jj += 4) {
          float4 vv = *(const float4*)&vb1[jj];
          float4 ev = *(float4*)&es[h1][jj];
          accv1 += vv.x*ev.x + vv.y*ev.y + vv.z*ev.z + vv.w*ev.w;
        }
      }
    }
    __syncthreads();   // es consumed before next tile overwrites
  }

  // denominators
  sparts += __shfl_xor(sparts, 16);
  sparts += __shfl_xor(sparts, 32);
  if (l < NH) sred[w][l] = sparts;
  __syncthreads();
  if (t < NH) {
    float sv = sred[0][t] + sred[1][t] + sred[2][t] + sred[3][t];
    ssum[t] = 1.0f / sv;
  }
  __syncthreads();

  float* sh = SH + (long)i * SHID + t;
  #pragma unroll
  for (int h = 0; h < NH; h++) sh[h * 304] = accop[h] * ssum[h];
  OVT[(long)i*480 + pair0] = accv0 * ssum[h0];
  if (pair1 < 480) OVT[(long)i*480 + pair1] = accv1 * ssum[h1];
}

// ---------------- ovp inverse transform + norm + shid fill ----------------
__global__ void k_ovp(const float* OVT, const float* R, const float* T, float* SH) {
  int idx = blockIdx.x * 256 + threadIdx.x;
  if (idx >= LSEQ * NH) return;
  int l = idx / NH, h = idx % NH;
  const float* o = OVT + (long)l*480 + h*40;
  float* sh = SH + (long)l * SHID + h * 304;
  #pragma unroll
  for (int d = 0; d < 16; d++) sh[256 + d] = o[d];
  const float* r = R + l*9;
  float t0 = T[l*3], t1 = T[l*3+1], t2 = T[l*3+2];
  #pragma unroll
  for (int v = 0; v < NV; v++) {
    float a = o[16+3*v+0] - t0, b = o[16+3*v+1] - t1, c = o[16+3*v+2] - t2;
    float x = r[0]*a + r[3]*b + r[6]*c;   // R^T
    float y = r[1]*a + r[4]*b + r[7]*c;
    float zz= r[2]*a + r[5]*b + r[8]*c;
    sh[272 + 3*v + 0] = x;
    sh[272 + 3*v + 1] = y;
    sh[272 + 3*v + 2] = zz;
    sh[296 + v] = sqrtf(x*x + y*y + zz*zz);
  }
}

// ---------------- layernorm: out = LN(res + y) * g + b ----------------
__global__ __launch_bounds__(384) void k_ln(const float* res, const float* y,
                                            const float* g, const float* b, float* out) {
  int l = blockIdx.x, t = threadIdx.x;
  __shared__ float red1[6], red2[6];
  __shared__ float mv[2];
  float x = res[(long)l * CS + t] + y[(long)l * CS + t];
  float s = x, s2 = x * x;
  #pragma unroll
  for (int off = 32; off >= 1; off >>= 1) { s += __shfl_xor(s, off); s2 += __shfl_xor(s2, off); }
  if ((t & 63) == 0) { red1[t >> 6] = s; red2[t >> 6] = s2; }
  __syncthreads();
  if (t == 0) {
    float ss = 0.f, ss2 = 0.f;
    #pragma unroll
    for (int u = 0; u < 6; u++) { ss += red1[u]; ss2 += red2[u]; }
    float m = ss / CS;
    float var = ss2 / CS - m * m;
    mv[0] = m; mv[1] = 1.0f / sqrtf(var + 1e-5f);
  }
  __syncthreads();
  out[(long)l * CS + t] = (x - mv[0]) * mv[1] * g[t] + b[t];
}

// ---------------- launcher ----------------
extern "C" void kernel_launch(void* const* d_in, const int* in_sizes, int n_in,
                              void* d_out, int out_size, void* d_ws, size_t ws_size,
                              hipStream_t stream) {
  const float* s    = (const float*)d_in[0];
  const float* z    = (const float*)d_in[1];
  const float* quat = (const float*)d_in[2];
  const float* trsl = (const float*)d_in[3];
  const float* Wq   = (const float*)d_in[4];
  const float* Wk   = (const float*)d_in[5];
  const float* Wv   = (const float*)d_in[6];
  const float* Wqp  = (const float*)d_in[7];
  const float* Wkp  = (const float*)d_in[8];
  const float* Wvp  = (const float*)d_in[9];
  const float* Wb   = (const float*)d_in[10];
  const float* Ws   = (const float*)d_in[11];
  const float* bs   = (const float*)d_in[12];
  const float* scale= (const float*)d_in[13];
  const float* g1   = (const float*)d_in[14];
  const float* b1   = (const float*)d_in[15];
  const float* Wm1  = (const float*)d_in[16];
  const float* bm1  = (const float*)d_in[17];
  const float* Wm2  = (const float*)d_in[18];
  const float* bm2  = (const float*)d_in[19];
  const float* Wm3  = (const float*)d_in[20];
  const float* bm3  = (const float*)d_in[21];
  const float* g2   = (const float*)d_in[22];
  const float* b2   = (const float*)d_in[23];
  float* out = (float*)d_out;

  float* p = (float*)d_ws;
  float* R    = p; p += 512*9;
  float* T    = p; p += 512*3;
  float* CH   = p; p += 16;
  unsigned short* WBP = (unsigned short*)p; p += (CZ*16)/2;
  float* Wcat = p; p += (long)CS*NALL;
  float* QPP  = p; p += LSEQ*144;
  float* KT   = p; p += NH*HD*LSEQ;
  float* KPT  = p; p += NH*12*LSEQ;
  float* VBT  = p; p += (long)NH*40*LSEQ;       // 245760
  float* LG   = p; p += (long)LSEQ*NH*LSEQ;     // 3.1M
  float* OVT  = p; p += (long)LSEQ*480;
  float* SH   = p; p += (long)LSEQ*SHID;
  float* S1   = p; p += LSEQ*CS;
  // zero zone (single memset): P, T1, H1, H2, H3
  float* ZB   = p;
  float* P    = p; p += (long)LSEQ*NALL;
  float* T1   = p; p += LSEQ*CS;
  float* H1   = p; p += LSEQ*CS;
  float* H2   = p; p += LSEQ*CS;
  float* H3   = p; p += LSEQ*CS;
  size_t zbytes = ((size_t)LSEQ*NALL + 4*LSEQ*CS) * sizeof(float);

  hipMemsetAsync(ZB, 0, zbytes, stream);
  k_prep<<<1, 512, 0, stream>>>(quat, trsl, scale, Wb, R, T, CH, WBP);
  k_concat<<<(CS*NALL + 255)/256, 256, 0, stream>>>(Wq, Wk, Wv, Wqp, Wkp, Wvp, Wcat);
  // P = s @ Wcat  (split-K=2, atomic into zeroed P)
  k_gemm<<<dim3(NALL/64, LSEQ/64, 2), 256, 0, stream>>>(
      s, Wcat, P, nullptr, CS, CS, NALL, NALL, 2, 0, 0);
  k_trans<<<dim3(24, 3), 256, 0, stream>>>(P, R, T, QPP, KT, KPT, VBT);
  k_logit<<<LSEQ/AI, 512, 0, stream>>>(P, QPP, KT, KPT, CH, LG);
  k_fused<<<LSEQ, 256, 0, stream>>>(z, WBP, LG, VBT, SH, OVT);
  k_ovp<<<(LSEQ*NH + 255)/256, 256, 0, stream>>>(OVT, R, T, SH);
  // T1 = SH @ Ws + bs  (split-K=12)
  k_gemm<<<dim3(CS/64, LSEQ/64, 12), 256, 0, stream>>>(
      SH, Ws, T1, bs, SHID, SHID, CS, CS, 12, 0, 0);
  k_ln<<<LSEQ, CS, 0, stream>>>(s, T1, g1, b1, S1);
  // MLP: split-K=8, relu fused into next GEMM's A-read
  k_gemm<<<dim3(CS/64, LSEQ/64, 8), 256, 0, stream>>>(
      S1, Wm1, H1, bm1, CS, CS, CS, CS, 8, 0, 0);
  k_gemm<<<dim3(CS/64, LSEQ/64, 8), 256, 0, stream>>>(
      H1, Wm2, H2, bm2, CS, CS, CS, CS, 8, 0, 1);
  k_gemm<<<dim3(CS/64, LSEQ/64, 8), 256, 0, stream>>>(
      H2, Wm3, H3, bm3, CS, CS, CS, CS, 8, 0, 1);
  k_ln<<<LSEQ, CS, 0, stream>>>(S1, H3, g2, b2, out);
}